// Round 5
// baseline (1004.588 us; speedup 1.0000x reference)
//
#include <hip/hip_runtime.h>

#define N_NODES 2048
#define KSEL 50

typedef float v2f __attribute__((ext_vector_type(2)));

// ---- order-preserving fp32 <-> uint map (monotone: bigger float => bigger uint)
__device__ __forceinline__ unsigned ford(float f) {
  unsigned b = __float_as_uint(f);
  return b ^ ((b & 0x80000000u) ? 0xFFFFFFFFu : 0x80000000u);
}
__device__ __forceinline__ float funord(unsigned u) {
  unsigned b = (u & 0x80000000u) ? (u ^ 0x80000000u) : ~u;
  return __uint_as_float(b);
}

// hist storage: bin b, sub-counter s (s = lane&1): word (b&63)*8 + (b>>6)*2 + s.
// Scan: lane reads words [lane*8, lane*8+8) = bins {g*64+lane} x {s} as 2x uint4.
#define HROW 516  // 512 + 4 pad: rows stagger 4 banks, 16B-aligned
__device__ __forceinline__ int hidx(unsigned b, int s) {
  return (int)(((b & 63u) << 3) | ((b >> 6) << 1)) | s;
}

// shared single-layer MLP tile: acc[16] = relu(bias + xs^T W), xs transposed layout
__device__ __forceinline__ void mlp_layer(float acc[16], const float* xs,
                                          const float* Ws, const float* bs,
                                          int r, int cg) {
  const float4* Ws4 = (const float4*)Ws;
#pragma unroll
  for (int i = 0; i < 16; ++i) acc[i] = bs[cg * 16 + i];
#pragma unroll 8
  for (int k = 0; k < 64; ++k) {
    float xv = xs[k * 65 + r];                   // banks (k+r)%32: 2-way, free
    float4 w0 = Ws4[k * 16 + cg * 4 + 0];        // wave-uniform broadcast
    float4 w1 = Ws4[k * 16 + cg * 4 + 1];
    float4 w2 = Ws4[k * 16 + cg * 4 + 2];
    float4 w3 = Ws4[k * 16 + cg * 4 + 3];
    acc[0]  += xv * w0.x; acc[1]  += xv * w0.y; acc[2]  += xv * w0.z; acc[3]  += xv * w0.w;
    acc[4]  += xv * w1.x; acc[5]  += xv * w1.y; acc[6]  += xv * w1.z; acc[7]  += xv * w1.w;
    acc[8]  += xv * w2.x; acc[9]  += xv * w2.y; acc[10] += xv * w2.z; acc[11] += xv * w2.w;
    acc[12] += xv * w3.x; acc[13] += xv * w3.y; acc[14] += xv * w3.z; acc[15] += xv * w3.w;
  }
#pragma unroll
  for (int i = 0; i < 16; ++i) acc[i] = fmaxf(acc[i], 0.f);
}

// Fused embedding: h1=relu(x@w0+b0); h2=relu(h1@w1+b1) -> A, AT; msg0=relu(h2@wm+bm) -> M
__global__ __launch_bounds__(256) void emb3_kernel(
    const float* __restrict__ x,
    const float* __restrict__ ew0, const float* __restrict__ eb0,
    const float* __restrict__ ew1, const float* __restrict__ eb1,
    const float* __restrict__ wmm, const float* __restrict__ bmm,
    float* __restrict__ outA, float* __restrict__ outAT, float* __restrict__ outM)
{
  const int tid = threadIdx.x;
  const int r = tid & 63, cg = tid >> 6;
  const size_t rowbase = (size_t)blockIdx.x * 64;
  __shared__ float xs[64 * 65];       // transposed: xs[c*65 + row]
  __shared__ float Ws[64 * 64];
  __shared__ float bs[64];
  float acc[16];

#pragma unroll
  for (int i = 0; i < 16; ++i) {
    int idx = tid + 256 * i;
    xs[(idx & 63) * 65 + (idx >> 6)] = x[rowbase * 64 + idx];
    Ws[idx] = ew0[idx];
  }
  if (tid < 64) bs[tid] = eb0[tid];
  __syncthreads();
  mlp_layer(acc, xs, Ws, bs, r, cg);             // h1
  __syncthreads();
#pragma unroll
  for (int i = 0; i < 16; ++i) {
    xs[(cg * 16 + i) * 65 + r] = acc[i];
    Ws[tid + 256 * i] = ew1[tid + 256 * i];
  }
  if (tid < 64) bs[tid] = eb1[tid];
  __syncthreads();
  mlp_layer(acc, xs, Ws, bs, r, cg);             // h2
  {
    float4* o4 = (float4*)(outA + (rowbase + r) * 64 + cg * 16);
#pragma unroll
    for (int q = 0; q < 4; ++q)
      o4[q] = make_float4(acc[q*4+0], acc[q*4+1], acc[q*4+2], acc[q*4+3]);
  }
  __syncthreads();
#pragma unroll
  for (int i = 0; i < 16; ++i) {
    xs[(cg * 16 + i) * 65 + r] = acc[i];
    Ws[tid + 256 * i] = wmm[tid + 256 * i];
  }
  if (tid < 64) bs[tid] = bmm[tid];
  __syncthreads();
  {   // flush AT (h2 transposed, feature-major)
    const size_t bb = rowbase >> 11;
    const int nbase = (int)(rowbase & 2047);
    const int c = tid >> 2, seg = tid & 3;
    float* oT = outAT + bb * 64 * N_NODES + (size_t)c * N_NODES + nbase + seg * 16;
#pragma unroll
    for (int q = 0; q < 4; ++q)
      ((float4*)oT)[q] = make_float4(xs[c*65+seg*16+q*4+0], xs[c*65+seg*16+q*4+1],
                                     xs[c*65+seg*16+q*4+2], xs[c*65+seg*16+q*4+3]);
  }
  mlp_layer(acc, xs, Ws, bs, r, cg);             // msg0
  {
    float4* o4 = (float4*)(outM + (rowbase + r) * 64 + cg * 16);
#pragma unroll
    for (int q = 0; q < 4; ++q)
      o4[q] = make_float4(acc[q*4+0], acc[q*4+1], acc[q*4+2], acc[q*4+3]);
  }
}

// plain single-layer linrelu (msg1)
__global__ __launch_bounds__(256) void linrelu_kernel(
    const float* __restrict__ in, const float* __restrict__ W,
    const float* __restrict__ bias, float* __restrict__ out)
{
  const int tid = threadIdx.x;
  const int r = tid & 63, cg = tid >> 6;
  const size_t rowbase = (size_t)blockIdx.x * 64;
  __shared__ float xs[64 * 65];
  __shared__ float Ws[64 * 64];
  __shared__ float bs[64];
  float acc[16];
#pragma unroll
  for (int i = 0; i < 16; ++i) {
    int idx = tid + 256 * i;
    xs[(idx & 63) * 65 + (idx >> 6)] = in[rowbase * 64 + idx];
    Ws[idx] = W[idx];
  }
  if (tid < 64) bs[tid] = bias[tid];
  __syncthreads();
  mlp_layer(acc, xs, Ws, bs, r, cg);
  float4* o4 = (float4*)(out + (rowbase + r) * 64 + cg * 16);
#pragma unroll
  for (int q = 0; q < 4; ++q)
    o4[q] = make_float4(acc[q*4+0], acc[q*4+1], acc[q*4+2], acc[q*4+3]);
}

// Fused: S = h_tile . h^T (8 rows x 2048): packed-fp32 FMA, in-place ford
// conversion (no duplicate uacc array -> no spills), adaptive radix select
// (skip common-prefix bytes, early probe-resolve), ballot-compacted extract.
template <bool FINAL>
__global__ __launch_bounds__(256, 4) void mp_kernel(
    const float* __restrict__ h, const float* __restrict__ hT,
    const float* __restrict__ msg,
    const float* __restrict__ wu, const float* __restrict__ bu,
    float* __restrict__ outp, float* __restrict__ outT)
{
  const int tid = threadIdx.x;
  const int lane = tid & 63;
  const int w64 = tid >> 6;
  const int bid = blockIdx.x;
  const int b = bid & 7;                  // round-robin blockIdx->XCD: 1 batch/XCD
  const int n0 = (bid >> 3) * 8;

  __shared__ float hrL[8 * 64];           // MP epilogue only
  __shared__ unsigned hist[8][HROW];      // sub-counter radix histograms
  __shared__ unsigned Lrow[8], pvS[8], TrowS[8], KcurS[8];
  __shared__ int shS[8], modeS[8];        // 0=HIST 1=PROBE 2=DONE
  __shared__ int sDone;
  __shared__ unsigned gtc[8], eqc[8];
  __shared__ unsigned LwMin[4][8], LwMax[4][8];
  __shared__ int seli[8][64];
  __shared__ float selv[8][64];
  __shared__ int eqlist[8][64];
  __shared__ float aggb[8 * 64];
  __shared__ float ot[64 * 9];

  const float* hb  = h  + (size_t)b * N_NODES * 64;
  const float* hTb = hT + (size_t)b * 64 * N_NODES;
  const float* colp = hTb + 4 * tid;

  float4 cur0, cur1, nxt0, nxt1;
  cur0 = *(const float4*)(colp);
  cur1 = *(const float4*)(colp + 1024);

  if (!FINAL) {
    hrL[tid]       = hb[(size_t)n0 * 64 + tid];
    hrL[tid + 256] = hb[(size_t)n0 * 64 + 256 + tid];
  }
  if (tid == 0) sDone = 0;
  if (tid < 8) { gtc[tid] = 0; eqc[tid] = 0; }
  for (int i = tid; i < 8 * HROW; i += 256) (&hist[0][0])[i] = 0;
  __syncthreads();

  // ---- S tile: value index t=r*8+j lives in acc2[r*4+(j>>1)][j&1];
  //      column m = (j>>2)*1024 + 4*tid + (j&3)
  v2f acc2[32];
#pragma unroll
  for (int i = 0; i < 32; ++i) { acc2[i][0] = 0.f; acc2[i][1] = 0.f; }

  const float* hrow = hb + (size_t)n0 * 64;   // block-uniform -> s_load path
  const float* cp = colp;

#pragma unroll 2
  for (int k4 = 0; k4 < 16; ++k4) {
    float4 a[8];
#pragma unroll
    for (int r = 0; r < 8; ++r)
      a[r] = *(const float4*)(hrow + r * 64 + k4 * 4);   // uniform scalar loads
#pragma unroll
    for (int kk = 0; kk < 4; ++kk) {
      const int k = k4 * 4 + kk;
      if (k < 63) {                                       // prefetch k+1 columns
        nxt0 = *(const float4*)(cp + 2048);
        nxt1 = *(const float4*)(cp + 2048 + 1024);
      }
      v2f c00 = {cur0.x, cur0.y}, c01 = {cur0.z, cur0.w};
      v2f c10 = {cur1.x, cur1.y}, c11 = {cur1.z, cur1.w};
#pragma unroll
      for (int r = 0; r < 8; ++r) {
        const float ar = ((const float*)&a[r])[kk];
        v2f as = {ar, ar};
        acc2[r*4+0] = __builtin_elementwise_fma(as, c00, acc2[r*4+0]);
        acc2[r*4+1] = __builtin_elementwise_fma(as, c01, acc2[r*4+1]);
        acc2[r*4+2] = __builtin_elementwise_fma(as, c10, acc2[r*4+2]);
        acc2[r*4+3] = __builtin_elementwise_fma(as, c11, acc2[r*4+3]);
      }
      cur0 = nxt0; cur1 = nxt1;
      cp += 2048;
    }
  }

  // ---- IN-PLACE: replace each S value with its ordered-uint bits (no 2nd array)
#pragma unroll
  for (int i = 0; i < 32; ++i) {
    acc2[i][0] = __uint_as_float(ford(acc2[i][0]));
    acc2[i][1] = __uint_as_float(ford(acc2[i][1]));
  }
#define UACC(r, j) __float_as_uint(acc2[(r)*4 + ((j) >> 1)][(j) & 1])

  // ---- prefilter: per row, L = max over waves of (wave-min of lane-max-of-8)
  //      (guarantees >=64 candidates >= L, so L <= T); M = row max.
#pragma unroll
  for (int rr = 0; rr < 8; ++rr) {
    unsigned mx = UACC(rr, 0);
#pragma unroll
    for (int j = 1; j < 8; ++j) { unsigned u = UACC(rr, j); mx = mx > u ? mx : u; }
    unsigned mn = mx, mxx = mx;
#pragma unroll
    for (int off = 32; off >= 1; off >>= 1) {
      unsigned o1 = (unsigned)__shfl_xor((int)mn, off, 64);
      unsigned o2 = (unsigned)__shfl_xor((int)mxx, off, 64);
      mn = mn < o1 ? mn : o1;
      mxx = mxx > o2 ? mxx : o2;
    }
    if (lane == 0) { LwMin[w64][rr] = mn; LwMax[w64][rr] = mxx; }
  }
  __syncthreads();
  if (tid < 8) {
    unsigned L = LwMin[0][tid], M = LwMax[0][tid];
#pragma unroll
    for (int w = 1; w < 4; ++w) {
      unsigned l = LwMin[w][tid], m = LwMax[w][tid];
      L = L > l ? L : l; M = M > m ? M : m;
    }
    Lrow[tid] = L;
    unsigned d = L ^ M;
    if (d == 0) {                       // >=64 exact copies of M: T = M
      modeS[tid] = 2; TrowS[tid] = M; atomicAdd(&sDone, 1);
    } else {
      int skipb = __builtin_clz(d) >> 3;          // common prefix, bytes
      int sh = 24 - 8 * skipb;                    // in {0,8,16,24}
      shS[tid] = sh;
      pvS[tid] = (unsigned)(((unsigned long long)L) >> (sh + 8));
      modeS[tid] = 0; KcurS[tid] = KSEL;
    }
  }
  __syncthreads();

  // ---- adaptive radix select: data-dependent #levels, probe when bin count==1
  const int sub = lane & 1;
  for (int it = 0; it < 4; ++it) {
    if (sDone == 8) break;                        // uniform
    // -- populate / probe phase
#pragma unroll
    for (int r = 0; r < 8; ++r) {
      const int md = modeS[r];
      if (md == 2) continue;
      const unsigned Lv = Lrow[r];
      const unsigned pr = pvS[r];
      const int shr = shS[r];
      if (md == 0) {
        unsigned* hrw = hist[r];
#pragma unroll
        for (int j = 0; j < 8; ++j) {
          unsigned u = UACC(r, j);
          bool act = (u >= Lv) &&
                     ((unsigned)(((unsigned long long)u) >> (shr + 8)) == pr);
          if (act) atomicAdd(&hrw[hidx((u >> shr) & 255u, sub)], 1u);
        }
      } else {                                    // PROBE: unique candidate = T
#pragma unroll
        for (int j = 0; j < 8; ++j) {
          unsigned u = UACC(r, j);
          if (u >= Lv && ((u >> (shr + 8)) == pr)) {
            TrowS[r] = u; modeS[r] = 2; atomicAdd(&sDone, 1);
          }
        }
      }
    }
    __syncthreads();
    // -- scan phase: wave w64 handles rows 2w,2w+1
#pragma unroll
    for (int q = 0; q < 2; ++q) {
      const int rr = w64 * 2 + q;
      if (modeS[rr] != 0) continue;
      unsigned* hrw = hist[rr];
      uint4 q0 = *(const uint4*)&hrw[lane * 8];
      uint4 q1 = *(const uint4*)&hrw[lane * 8 + 4];
      *(uint4*)&hrw[lane * 8]     = make_uint4(0,0,0,0);
      *(uint4*)&hrw[lane * 8 + 4] = make_uint4(0,0,0,0);
      unsigned c0 = q0.x + q0.y, c1 = q0.z + q0.w;
      unsigned c2 = q1.x + q1.y, c3 = q1.z + q1.w;
      unsigned s0 = c0, s1 = c1, s2 = c2, s3 = c3;        // suffix over lanes
#pragma unroll
      for (int off = 1; off < 64; off <<= 1) {
        unsigned t0=__shfl_down((int)s0,off,64), t1=__shfl_down((int)s1,off,64);
        unsigned t2=__shfl_down((int)s2,off,64), t3=__shfl_down((int)s3,off,64);
        if (lane + off < 64) { s0+=t0; s1+=t1; s2+=t2; s3+=t3; }
      }
      unsigned T1=(unsigned)__shfl((int)s1,0,64), T2=(unsigned)__shfl((int)s2,0,64);
      unsigned T3=(unsigned)__shfl((int)s3,0,64);
      const unsigned Kc = KcurS[rr];
      unsigned cA[4] = {c0, c1, c2, c3};
      unsigned AA[4] = {s0 - c0 + T1 + T2 + T3, s1 - c1 + T2 + T3,
                        s2 - c2 + T3,           s3 - c3};
#pragma unroll
      for (int g = 0; g < 4; ++g) {
        if (AA[g] < Kc && Kc <= AA[g] + cA[g]) {  // unique (lane,g) fires
          unsigned bin = (unsigned)(g * 64 + lane);
          unsigned pvn = (pvS[rr] << 8) | bin;
          int shn = shS[rr] - 8;
          KcurS[rr] = Kc - AA[g];
          if (shn < 0)          { TrowS[rr] = pvn; modeS[rr] = 2; atomicAdd(&sDone, 1); }
          else                  { pvS[rr] = pvn; shS[rr] = shn;
                                  if (cA[g] == 1) modeS[rr] = 1; }
        }
      }
    }
    __syncthreads();
  }

  // ---- extract winners (> T) and tie candidates (== T), ballot-compacted
#pragma unroll
  for (int r = 0; r < 8; ++r) {
    const unsigned T = TrowS[r];
#pragma unroll
    for (int j = 0; j < 8; ++j) {
      const unsigned u = UACC(r, j);
      const int m = (j >> 2) * 1024 + 4 * tid + (j & 3);
      unsigned long long mk = __ballot(u > T);
      if (mk) {
        int fs = __ffsll(mk) - 1;
        unsigned base = 0;
        if (lane == fs) base = atomicAdd(&gtc[r], (unsigned)__popcll(mk));
        base = (unsigned)__shfl((int)base, fs, 64);
        if (u > T) {
          int pos = (int)base + __popcll(mk & ((1ULL << lane) - 1ULL));
          seli[r][pos] = m; selv[r][pos] = funord(u);
        }
      }
      unsigned long long mk2 = __ballot(u == T);
      if (mk2) {
        int fs = __ffsll(mk2) - 1;
        unsigned base = 0;
        if (lane == fs) base = atomicAdd(&eqc[r], (unsigned)__popcll(mk2));
        base = (unsigned)__shfl((int)base, fs, 64);
        if (u == T) {
          int pos = (int)base + __popcll(mk2 & ((1ULL << lane) - 1ULL));
          if (pos < 64) eqlist[r][pos] = m;
        }
      }
    }
  }
  __syncthreads();

  // ---- resolve ties: `need` smallest indices among equals (jax order)
  if (tid < 8) {
    const int r = tid;
    const int g = (int)gtc[r];
    const int need = KSEL - g;
    const int e = (eqc[r] < 64u) ? (int)eqc[r] : 64;
    const float Tf = funord(TrowS[r]);
    for (int t = 0; t < need; ++t) {
      int bestp = -1, bestm = 0x7FFFFFFF;
      for (int i = 0; i < e; ++i) {
        int mm = eqlist[r][i];
        if (mm < bestm) { bestm = mm; bestp = i; }
      }
      if (bestp < 0) break;
      eqlist[r][bestp] = 0x7FFFFFFF;
      seli[r][g + t] = bestm;
      selv[r][g + t] = Tf;
    }
  }
  __syncthreads();

  if constexpr (FINAL) {
    float* ob = outp + ((size_t)b * N_NODES + n0) * N_NODES;
#pragma unroll
    for (int r = 0; r < 8; ++r) {
      const unsigned T = TrowS[r];
      const int g = (int)gtc[r];
      const int need = KSEL - g;
#pragma unroll
      for (int p = 0; p < 2; ++p) {
        float4 w; float* wf = (float*)&w;
#pragma unroll
        for (int e = 0; e < 4; ++e) {
          const unsigned u = UACC(r, p * 4 + e);
          const int m = p * 1024 + 4 * tid + e;
          bool keep = u > T;
          if (u == T) {
            for (int i = 0; i < need; ++i)
              if (seli[r][g + i] == m) { keep = true; break; }
          }
          wf[e] = keep ? funord(u) : 0.f;
        }
        *(float4*)(ob + (size_t)r * N_NODES + p * 1024 + 4 * tid) = w;
      }
    }
  } else {
    // sparse aggregation: agg[r][:] = sum_i v_i * msg[m_i][:]
    {
      const int r = tid >> 5;
      const int ln = tid & 31;
      const float* msgb = msg + (size_t)b * N_NODES * 64;
      float a0 = 0.f, a1 = 0.f;
      for (int i = 0; i < KSEL; ++i) {
        int mi = seli[r][i];
        float vv = selv[r][i];
        const float* mr = msgb + (size_t)mi * 64;
        a0 += vv * mr[ln];
        a1 += vv * mr[ln + 32];
      }
      aggb[r * 64 + ln] = a0;
      aggb[r * 64 + ln + 32] = a1;
    }
    __syncthreads();
    // update MLP, column-per-lane: c = tid&63, rows rg, rg+1 (wu loads shared)
    const int c = tid & 63;
    const int rg = (tid >> 6) * 2;
    float s0 = bu[c], s1 = bu[c];
#pragma unroll 8
    for (int jj = 0; jj < 64; ++jj) {
      float wv = wu[jj * 64 + c];                 // coalesced, used for 2 rows
      s0 += hrL[rg * 64 + jj] * wv;               // LDS broadcast
      s1 += hrL[(rg + 1) * 64 + jj] * wv;
    }
#pragma unroll 8
    for (int jj = 0; jj < 64; ++jj) {
      float wv = wu[(64 + jj) * 64 + c];
      s0 += aggb[rg * 64 + jj] * wv;
      s1 += aggb[(rg + 1) * 64 + jj] * wv;
    }
    s0 = fmaxf(s0, 0.f); s1 = fmaxf(s1, 0.f);
    outp[((size_t)b * N_NODES + n0 + rg) * 64 + c] = s0;
    outp[((size_t)b * N_NODES + n0 + rg + 1) * 64 + c] = s1;
    ot[c * 9 + rg] = s0;                          // stride 9: conflict-free
    ot[c * 9 + rg + 1] = s1;
    __syncthreads();
    for (int i = tid; i < 512; i += 256) {        // flush h2T (32B segments)
      int f = i >> 3, rr = i & 7;
      outT[(size_t)b * 64 * N_NODES + (size_t)f * N_NODES + n0 + rr] = ot[f * 9 + rr];
    }
  }
}

extern "C" void kernel_launch(void* const* d_in, const int* in_sizes, int n_in,
                              void* d_out, int out_size, void* d_ws, size_t ws_size,
                              hipStream_t stream)
{
  (void)in_sizes; (void)n_in; (void)out_size; (void)ws_size;
  const float* x   = (const float*)d_in[0];
  const float* ew0 = (const float*)d_in[1];
  const float* eb0 = (const float*)d_in[2];
  const float* ew1 = (const float*)d_in[3];
  const float* eb1 = (const float*)d_in[4];
  const float* w0m = (const float*)d_in[5];
  const float* b0m = (const float*)d_in[6];
  const float* w0u = (const float*)d_in[7];
  const float* b0u = (const float*)d_in[8];
  const float* w1m = (const float*)d_in[9];
  const float* b1m = (const float*)d_in[10];
  const float* w1u = (const float*)d_in[11];
  const float* b1u = (const float*)d_in[12];
  float* out = (float*)d_out;
  float* ws = (float*)d_ws;

  const size_t BUF = (size_t)8 * N_NODES * 64;  // 4 MB each, 20 MB total
  float* A   = ws;
  float* AT  = ws + 1 * BUF;
  float* Bf  = ws + 2 * BUF;
  float* BfT = ws + 3 * BUF;
  float* C   = ws + 4 * BUF;

  // fused embedding (2 layers) + msg0
  emb3_kernel<<<256, 256, 0, stream>>>(x, ew0, eb0, ew1, eb1, w0m, b0m, A, AT, C);

  // MP layer 0 (consumes msg0=C, produces Bf/BfT)
  mp_kernel<false><<<2048, 256, 0, stream>>>(A, AT, C, w0u, b0u, Bf, BfT);

  // msg1
  linrelu_kernel<<<256, 256, 0, stream>>>(Bf, w1m, b1m, C);

  // MP layer 1
  mp_kernel<false><<<2048, 256, 0, stream>>>(Bf, BfT, C, w1u, b1u, A, AT);

  // final dense top-k adjacency
  mp_kernel<true><<<2048, 256, 0, stream>>>(A, AT, nullptr, nullptr, nullptr, out, nullptr);
}